// Round 2
// baseline (1082.197 us; speedup 1.0000x reference)
//
#include <hip/hip_runtime.h>

// Problem constants
#define BB 64
#define TT 4
#define NOBJ 6
#define RTOT 1536   // B*T*N
#define DD 256

struct MatDesc { const float* src; float* dst; int kshift; int stride; int coff; };
struct MatDescs { MatDesc m[28]; };

#define FMA4(ACC, A4, W4) do { \
  ACC = fmaf((A4).x, (W4).x, ACC); \
  ACC = fmaf((A4).y, (W4).y, ACC); \
  ACC = fmaf((A4).z, (W4).z, ACC); \
  ACC = fmaf((A4).w, (W4).w, ACC); } while(0)

// ---- prep: transpose N=256 weight mats into WT[kq][d][4] layout ----
__global__ void prep_mats(MatDescs md) {
  const MatDesc de = md.m[blockIdx.y];
  int K = 1 << de.kshift;
  int idx = blockIdx.x * 256 + threadIdx.x;
  if (idx >= (256 << de.kshift)) return;
  int d = idx >> de.kshift;
  int kk = idx & (K - 1);
  de.dst[(kk >> 2) * 1024 + d * 4 + (kk & 3)] = de.src[d * de.stride + de.coff + kk];
}

// ---- prep conv2 weights: w2q[((ci*3+ky)*8+coq)*24 + cj*3+kx] ----
__global__ void prep_convw(const float* __restrict__ w2, float* __restrict__ w2q) {
  int i2 = blockIdx.x * 256 + threadIdx.x;
  if (i2 >= 36864) return;
  int kx = i2 % 3, cj = (i2 / 3) & 7, coq = (i2 / 24) & 7, ky = (i2 / 192) % 3, ci = i2 / 576;
  w2q[i2] = w2[((coq * 8 + cj) * 64 + ci) * 9 + ky * 3 + kx];
}

// ---- r = mean_t(((y2-y1)/2 + (x2-x1)/2)/2) ----
__global__ void r_kernel(const float* __restrict__ rois, float* __restrict__ rbuf) {
  int i = blockIdx.x * 256 + threadIdx.x;
  if (i >= BB * NOBJ) return;
  int b = i / NOBJ, n = i % NOBJ;
  float acc = 0.f;
  for (int t = 0; t < TT; t++) {
    const float* rp = rois + ((b * TT + t) * NOBJ + n) * 5;
    acc += (rp[4] - rp[2]) * 0.5f + (rp[3] - rp[1]) * 0.5f;
  }
  rbuf[i] = acc * 0.125f;   // /2 then mean over T=4
}

// ---- fused conv1+conv2: x (256,3,128,128) -> relu conv1 s2 -> relu conv2 s2 -> feat2 (256,64,32,32)
// Per block: image n, feat2 rows oy0..oy0+3. feat1 rows 2*oy0..2*oy0+8 (9) computed in LDS
// in 16 chunks of 4 channels; x rows 4*oy0..4*oy0+18 (19) staged once in LDS.
// SAME pad (stride2,k3): pad_lo=0, pad_hi=1 on both dims for both convs.
__global__ __launch_bounds__(512, 4) void convf_kernel(const float* __restrict__ x,
                                                       const float* __restrict__ w1,
                                                       const float* __restrict__ b1,
                                                       const float* __restrict__ w2q,
                                                       const float* __restrict__ b2,
                                                       float* __restrict__ feat2) {
  __shared__ __align__(16) float xs[3 * 19 * 132];   // 30,096 B; cols 0..127 data, 128..131 zero
  __shared__ __align__(16) float f1c[4 * 9 * 72];    // 10,368 B; cols 0..63 data, 64..67 zero
  __shared__ float w1s[1728];
  __shared__ float b1s[64];
  int bx = blockIdx.x;
  int n = bx >> 3;
  int oy0 = (bx & 7) * 4;
  int f1base = 2 * oy0;    // first feat1 row in tile (rows f1base..f1base+8; row>=64 is zero pad)
  int xbase = 4 * oy0;     // first x row staged (rows xbase..xbase+18; row>=128 zero)
  int tid = threadIdx.x;
  for (int i = tid; i < 1728; i += 512) w1s[i] = w1[i];
  if (tid < 64) b1s[tid] = b1[tid];
  for (int i = tid; i < 3 * 19 * 33; i += 512) {
    int c4 = i % 33;
    int row = (i / 33) % 19;
    int ci = i / (33 * 19);
    int gr = xbase + row;
    float4 v = {0.f, 0.f, 0.f, 0.f};
    if (gr < 128 && c4 < 32)
      v = *(const float4*)(x + ((n * 3 + ci) * 128 + gr) * 128 + c4 * 4);
    *(float4*)&xs[(ci * 19 + row) * 132 + c4 * 4] = v;
  }
  int w8 = tid >> 6;
  int coq = __builtin_amdgcn_readfirstlane(w8);   // co = coq*8 + cj
  int l = tid & 63;
  int r = l >> 4;     // output row 0..3
  int cp = l & 15;    // cols 2cp, 2cp+1
  float acc[8][2] = {};
  for (int cc = 0; cc < 16; cc++) {
    __syncthreads();   // first iter: covers staging; later: f1c reads done before overwrite
    // conv1 phase: f1c[cl][r9][0..67] for co1 = cc*4+cl
    for (int i = tid; i < 612; i += 512) {    // 4*9*17
      int c4 = i % 17;
      int r9 = (i / 17) % 9;
      int cl = i / 153;
      float4 o = {0.f, 0.f, 0.f, 0.f};
      if (c4 < 16 && f1base + r9 < 64) {
        int co1 = cc * 4 + cl;
        const float* wp = &w1s[co1 * 27];
        #pragma unroll
        for (int ci = 0; ci < 3; ci++)
          #pragma unroll
          for (int ky = 0; ky < 3; ky++) {
            const float* xp = &xs[(ci * 19 + 2 * r9 + ky) * 132 + c4 * 8];
            float xv[9];
            #pragma unroll
            for (int t = 0; t < 9; t++) xv[t] = xp[t];
            #pragma unroll
            for (int kx = 0; kx < 3; kx++) {
              float wv = wp[ci * 9 + ky * 3 + kx];
              o.x = fmaf(xv[kx], wv, o.x);
              o.y = fmaf(xv[kx + 2], wv, o.y);
              o.z = fmaf(xv[kx + 4], wv, o.z);
              o.w = fmaf(xv[kx + 6], wv, o.w);
            }
          }
        float bb = b1s[co1];
        o.x = fmaxf(o.x + bb, 0.f); o.y = fmaxf(o.y + bb, 0.f);
        o.z = fmaxf(o.z + bb, 0.f); o.w = fmaxf(o.w + bb, 0.f);
      }
      *(float4*)&f1c[(cl * 9 + r9) * 72 + c4 * 4] = o;
    }
    __syncthreads();
    // conv2 partial accumulate over these 4 channels
    #pragma unroll
    for (int cl = 0; cl < 4; cl++) {
      int ci = cc * 4 + cl;
      #pragma unroll
      for (int ky = 0; ky < 3; ky++) {
        int rl = 2 * r + ky;
        const float* lp = &f1c[(cl * 9 + rl) * 72 + cp * 4];
        float4 t4 = *(const float4*)lp;
        float2 t2 = *(const float2*)(lp + 4);
        float rr6[6] = {t4.x, t4.y, t4.z, t4.w, t2.x, t2.y};
        const float* wp = &w2q[((ci * 3 + ky) * 8 + coq) * 24];
        #pragma unroll
        for (int cj = 0; cj < 8; cj++)
          #pragma unroll
          for (int kx = 0; kx < 3; kx++) {
            float wv = wp[cj * 3 + kx];
            acc[cj][0] = fmaf(rr6[kx], wv, acc[cj][0]);
            acc[cj][1] = fmaf(rr6[kx + 2], wv, acc[cj][1]);
          }
      }
    }
  }
  int oy = oy0 + r;
  #pragma unroll
  for (int cj = 0; cj < 8; cj++) {
    float bias = b2[coq * 8 + cj];
    float2 ov;
    ov.x = fmaxf(acc[cj][0] + bias, 0.f);
    ov.y = fmaxf(acc[cj][1] + bias, 0.f);
    *(float2*)&feat2[((n * 64 + coq * 8 + cj) * 32 + oy) * 32 + cp * 2] = ov;
  }
}

// ---- ROI align: feat2 (256,64,32,32) + rois(1536,5) -> pool (1536, 64*4*4) c-major ----
__global__ void roi_pool_kernel(const float* __restrict__ feat2, const float* __restrict__ rois,
                                float* __restrict__ pool) {
  int o = blockIdx.x * 256 + threadIdx.x;
  if (o >= RTOT * 1024) return;
  int px = o & 3, py = (o >> 2) & 3, c = (o >> 4) & 63, r = o >> 10;
  const float* rp = rois + r * 5;
  int bi = (int)rp[0];
  float x1 = rp[1] * 0.25f, y1 = rp[2] * 0.25f, x2 = rp[3] * 0.25f, y2 = rp[4] * 0.25f;
  float bw = fmaxf(x2 - x1, 1.0f) * 0.25f;
  float bh = fmaxf(y2 - y1, 1.0f) * 0.25f;
  float sx = x1 + bw * (px + 0.5f);
  float sy = y1 + bh * (py + 0.5f);
  float x0f = fminf(fmaxf(floorf(sx), 0.f), 31.f);
  float y0f = fminf(fmaxf(floorf(sy), 0.f), 31.f);
  float lx = fminf(fmaxf(sx - x0f, 0.f), 1.f);
  float ly = fminf(fmaxf(sy - y0f, 0.f), 1.f);
  int ix0 = (int)x0f, iy0 = (int)y0f;
  int ix1 = min(ix0 + 1, 31), iy1 = min(iy0 + 1, 31);
  const float* f = feat2 + (bi * 64 + c) * 1024;
  float v00 = f[iy0 * 32 + ix0], v01 = f[iy0 * 32 + ix1];
  float v10 = f[iy1 * 32 + ix0], v11 = f[iy1 * 32 + ix1];
  pool[o] = v00 * (1 - ly) * (1 - lx) + v01 * (1 - ly) * lx + v10 * ly * (1 - lx) + v11 * ly * lx;
}

// ---- emb1: (1536,2)@(256,2)^T + b, relu ----
__global__ void emb1_kernel(const float* __restrict__ coor, const float* __restrict__ w,
                            const float* __restrict__ b, float* __restrict__ out) {
  int o = blockIdx.x * 256 + threadIdx.x;
  if (o >= RTOT * DD) return;
  int c = o & 255, r = o >> 8;
  float v = coor[r * 2] * w[c * 2] + coor[r * 2 + 1] * w[c * 2 + 1] + b[c];
  out[o] = fmaxf(v, 0.f);
}

// ---- generic broadcast-row GEMM + bias + relu: C[r, coff+d] = relu(A[r,:K] . WT[:,d] + bias[d]) ----
__global__ __launch_bounds__(512) void gemmB_kernel(const float* __restrict__ A, int lda,
                                                    const float* __restrict__ WT,
                                                    const float* __restrict__ bias,
                                                    float* __restrict__ C, int ldc, int coff,
                                                    int kshift) {
  __shared__ __align__(16) float As[8 * 1024];
  int K = 1 << kshift;
  int tid = threadIdx.x;
  int r0 = blockIdx.x * 8;
  for (int idx = tid; idx < 8 * K; idx += 512)
    As[idx] = A[(r0 + (idx >> kshift)) * lda + (idx & (K - 1))];
  __syncthreads();
  int d = tid & 255;
  int half = __builtin_amdgcn_readfirstlane(tid >> 8);
  float acc[4] = {};
  const float* asb = As + half * 4 * K;
  for (int kq = 0; kq < (K >> 2); kq++) {
    float4 wv = *(const float4*)(WT + kq * 1024 + d * 4);
    #pragma unroll
    for (int rr = 0; rr < 4; rr++) {
      float4 a4 = *(const float4*)(asb + rr * K + kq * 4);
      FMA4(acc[rr], a4, wv);
    }
  }
  float bv = bias[d];
  #pragma unroll
  for (int rr = 0; rr < 4; rr++)
    C[(r0 + half * 4 + rr) * ldc + coff + d] = fmaxf(acc[rr] + bv, 0.f);
}

// ---- internet kernel: one block per (b,k); computes cs[b,:,k*256+:] ----
__global__ __launch_bounds__(512) void internet_kernel(
    int j, const float* __restrict__ obj, const float* __restrict__ sbuf,
    const float* __restrict__ src_coor, const float* __restrict__ dout,
    const float* __restrict__ rbuf, float* __restrict__ cs,
    const float* __restrict__ selfT, const float* __restrict__ uT,
    const float* __restrict__ vT, const float* __restrict__ affT,
    const float* __restrict__ outAT, const float* __restrict__ outST,
    const float* __restrict__ self_b, const float* __restrict__ rel_b,
    const float* __restrict__ aff_b, const float* __restrict__ out_b) {
  __shared__ __align__(16) float s_lds[6 * 256];
  __shared__ __align__(16) float v_lds[6 * 256];
  __shared__ __align__(16) float h_lds[6 * 256];
  __shared__ __align__(16) float a_lds[6 * 256];
  __shared__ float coor_lds[12], r_lds[6], mw[6][8];
  int bx = blockIdx.x;
  int xcd = bx & 7;
  int k = __builtin_amdgcn_readfirstlane(xcd >> 1);           // XCD-swizzle: one k per XCD-pair
  int b = __builtin_amdgcn_readfirstlane(((xcd & 1) << 5) + (bx >> 3));
  int sl = j + k;
  int tid = threadIdx.x;
  const float* srow = (sl < 4) ? (obj + (b * 4 + sl) * 6 * 256)
                               : (sbuf + ((sl - 4) * 64 + b) * 6 * 256);
  for (int idx = tid; idx < 1536; idx += 512) s_lds[idx] = srow[idx];
  if (tid < 12) {
    int i = tid >> 1, c = tid & 1;
    coor_lds[tid] = (sl < 4) ? src_coor[((b * 4 + sl) * 6 + i) * 2 + c]
                             : dout[((b * 8 + (sl - 4)) * 6 + i) * 4 + 2 + c];
  }
  if (tid < 6) r_lds[tid] = rbuf[b * 6 + tid];
  __syncthreads();
  if (tid < 36) {
    int i = tid / 6, jj = tid % 6;
    float dx = coor_lds[i * 2] - coor_lds[jj * 2];
    float dy = coor_lds[i * 2 + 1] - coor_lds[jj * 2 + 1];
    float dist = sqrtf(dx * dx + dy * dy);
    mw[i][jj] = (i != jj && dist <= r_lds[i] + r_lds[jj]) ? 1.f : 0.f;
  }
  int d = tid & 255;
  int half = __builtin_amdgcn_readfirstlane(tid >> 8);
  const float* sT = selfT + k * 65536;
  const float* uTk = uT + k * 65536;
  const float* vTk = vT + k * 65536;
  const float* sbase = s_lds + half * 3 * 256;
  float as[3] = {}, au[3] = {}, av[3] = {};
  for (int kq = 0; kq < 64; kq++) {
    float4 ws = *(const float4*)(sT + kq * 1024 + d * 4);
    float4 wu = *(const float4*)(uTk + kq * 1024 + d * 4);
    float4 wv = *(const float4*)(vTk + kq * 1024 + d * 4);
    #pragma unroll
    for (int rr = 0; rr < 3; rr++) {
      float4 a4 = *(const float4*)(sbase + rr * 256 + kq * 4);
      FMA4(as[rr], a4, ws);
      FMA4(au[rr], a4, wu);
      FMA4(av[rr], a4, wv);
    }
  }
  #pragma unroll
  for (int rr = 0; rr < 3; rr++) v_lds[(half * 3 + rr) * 256 + d] = av[rr];
  __syncthreads();
  float sbv = self_b[k * 256 + d];
  float rbv = rel_b[k * 256 + d];
  #pragma unroll
  for (int rr = 0; rr < 3; rr++) {
    int i = half * 3 + rr;
    float cnt = mw[i][0] + mw[i][1] + mw[i][2] + mw[i][3] + mw[i][4] + mw[i][5];
    float relsum = cnt * (au[rr] + rbv);
    #pragma unroll
    for (int jj = 0; jj < 6; jj++)
      relsum = fmaf(mw[i][jj], v_lds[jj * 256 + d], relsum);
    h_lds[i * 256 + d] = as[rr] + sbv + relsum;
  }
  __syncthreads();
  const float* aT = affT + k * 65536;
  const float* hbase = h_lds + half * 3 * 256;
  float aa[3] = {};
  for (int kq = 0; kq < 64; kq++) {
    float4 wv = *(const float4*)(aT + kq * 1024 + d * 4);
    #pragma unroll
    for (int rr = 0; rr < 3; rr++) {
      float4 a4 = *(const float4*)(hbase + rr * 256 + kq * 4);
      FMA4(aa[rr], a4, wv);
    }
  }
  float abv = aff_b[k * 256 + d];
  #pragma unroll
  for (int rr = 0; rr < 3; rr++)
    a_lds[(half * 3 + rr) * 256 + d] = fmaxf(aa[rr] + abv, 0.f);
  __syncthreads();
  const float* oaT = outAT + k * 65536;
  const float* osT = outST + k * 65536;
  const float* abase = a_lds + half * 3 * 256;
  float ao[3] = {};
  for (int kq = 0; kq < 64; kq++) {
    float4 wa = *(const float4*)(oaT + kq * 1024 + d * 4);
    float4 wsv = *(const float4*)(osT + kq * 1024 + d * 4);
    #pragma unroll
    for (int rr = 0; rr < 3; rr++) {
      float4 a4 = *(const float4*)(abase + rr * 256 + kq * 4);
      float4 s4 = *(const float4*)(sbase + rr * 256 + kq * 4);
      FMA4(ao[rr], a4, wa);
      FMA4(ao[rr], s4, wsv);
    }
  }
  float obv = out_b[k * 256 + d];
  #pragma unroll
  for (int rr = 0; rr < 3; rr++)
    cs[(b * 6 + half * 3 + rr) * 1024 + k * 256 + d] = fmaxf(ao[rr] + obv, 0.f);
}

// ---- agg + dec: one block per b ----
__global__ __launch_bounds__(512) void agg_kernel(int j, const float* __restrict__ cs,
                                                  const float* __restrict__ aggT,
                                                  const float* __restrict__ agg_b,
                                                  const float* __restrict__ decw,
                                                  const float* __restrict__ decb,
                                                  float* __restrict__ sbuf,
                                                  float* __restrict__ dout) {
  __shared__ __align__(16) float cs_lds[6 * 1024];
  __shared__ __align__(16) float sn_lds[6 * 256];
  int b = blockIdx.x;
  int tid = threadIdx.x;
  for (int idx = tid; idx < 6144; idx += 512) cs_lds[idx] = cs[b * 6144 + idx];
  __syncthreads();
  int d = tid & 255;
  int half = __builtin_amdgcn_readfirstlane(tid >> 8);
  float acc[3] = {};
  const float* cbase = cs_lds + half * 3 * 1024;
  for (int kq = 0; kq < 256; kq++) {
    float4 wv = *(const float4*)(aggT + kq * 1024 + d * 4);
    #pragma unroll
    for (int rr = 0; rr < 3; rr++) {
      float4 a4 = *(const float4*)(cbase + rr * 1024 + kq * 4);
      FMA4(acc[rr], a4, wv);
    }
  }
  float bv = agg_b[d];
  #pragma unroll
  for (int rr = 0; rr < 3; rr++) {
    int i = half * 3 + rr;
    float v = acc[rr] + bv;              // no relu on agg
    sn_lds[i * 256 + d] = v;
    sbuf[((j * 64 + b) * 6 + i) * 256 + d] = v;
  }
  __syncthreads();
  if (tid < 384) {
    int lane16 = tid & 15;
    int p = tid >> 4;      // 0..23
    int i = p >> 2, o = p & 3;
    float a2 = 0.f;
    #pragma unroll
    for (int m = 0; m < 16; m++) {
      int dd = lane16 + m * 16;
      a2 = fmaf(sn_lds[i * 256 + dd], decw[o * 256 + dd], a2);
    }
    a2 += __shfl_down(a2, 8, 16);
    a2 += __shfl_down(a2, 4, 16);
    a2 += __shfl_down(a2, 2, 16);
    a2 += __shfl_down(a2, 1, 16);
    if (lane16 == 0) dout[((b * 8 + j) * 6 + i) * 4 + o] = a2 + decb[o];
  }
}

extern "C" void kernel_launch(void* const* d_in, const int* in_sizes, int n_in,
                              void* d_out, int out_size, void* d_ws, size_t ws_size,
                              hipStream_t stream) {
  const float* x        = (const float*)d_in[0];
  const float* rois     = (const float*)d_in[1];
  const float* src_coor = (const float*)d_in[2];
  const float* w_conv1  = (const float*)d_in[3];
  const float* b_conv1  = (const float*)d_in[4];
  const float* w_conv2  = (const float*)d_in[5];
  const float* b_conv2  = (const float*)d_in[6];
  const float* fc0_w    = (const float*)d_in[7];
  const float* fc0_b    = (const float*)d_in[8];
  const float* fc0c_w   = (const float*)d_in[9];
  const float* fc0c_b   = (const float*)d_in[10];
  const float* fc1c_w   = (const float*)d_in[11];
  const float* fc1c_b   = (const float*)d_in[12];
  const float* red_w    = (const float*)d_in[13];
  const float* red_b    = (const float*)d_in[14];
  const float* g_self_w = (const float*)d_in[15];
  const float* g_self_b = (const float*)d_in[16];
  const float* g_rel_w  = (const float*)d_in[17];
  const float* g_rel_b  = (const float*)d_in[18];
  const float* g_aff_w  = (const float*)d_in[19];
  const float* g_aff_b  = (const float*)d_in[20];
  const float* g_out_w  = (const float*)d_in[21];
  const float* g_out_b  = (const float*)d_in[22];
  const float* agg_w    = (const float*)d_in[23];
  const float* agg_b    = (const float*)d_in[24];
  const float* dec_w    = (const float*)d_in[25];
  const float* dec_b    = (const float*)d_in[26];
  float* out = (float*)d_out;

  float* ws = (float*)d_ws;
  size_t off = 0;
  auto alloc = [&](size_t nf) { float* p = ws + off; off += (nf + 63) & ~(size_t)63; return p; };
  float* feat2 = alloc(16777216);   // (256,64,32,32)
  float* pool  = alloc(1572864);    // (1536,1024)
  float* cat   = alloc(786432);     // (1536,512)
  float* emb1  = alloc(393216);     // (1536,256)
  float* obj   = alloc(393216);     // (B,T,N,256) = state slots 0..3
  float* sbuf  = alloc(786432);     // (8,B,N,256) = state slots 4..11
  float* cs    = alloc(393216);     // (B,N,1024)
  float* rbuf  = alloc(384);
  float* fc0T  = alloc(262144);
  float* fc1cT = alloc(65536);
  float* redT  = alloc(131072);
  float* aggT  = alloc(262144);
  float* selfT = alloc(262144);
  float* uT    = alloc(262144);
  float* vT    = alloc(262144);
  float* affT  = alloc(262144);
  float* outAT = alloc(262144);
  float* outST = alloc(262144);
  float* w2q   = alloc(36864);
  // total ~23.5M floats ~94 MB

  MatDescs md;
  int mi = 0;
  auto add = [&](const float* s, float* dstp, int ksh, int stride, int coff) {
    md.m[mi].src = s; md.m[mi].dst = dstp; md.m[mi].kshift = ksh;
    md.m[mi].stride = stride; md.m[mi].coff = coff; mi++;
  };
  add(fc0_w,  fc0T,  10, 1024, 0);
  add(fc1c_w, fc1cT, 8,  256,  0);
  add(red_w,  redT,  9,  512,  0);
  add(agg_w,  aggT,  10, 1024, 0);
  for (int k = 0; k < 4; k++) {
    add(g_self_w + k * 65536,  selfT + k * 65536, 8, 256, 0);
    add(g_rel_w  + k * 131072, uT    + k * 65536, 8, 512, 0);
    add(g_rel_w  + k * 131072, vT    + k * 65536, 8, 512, 256);
    add(g_aff_w  + k * 65536,  affT  + k * 65536, 8, 256, 0);
    add(g_out_w  + k * 131072, outAT + k * 65536, 8, 512, 0);
    add(g_out_w  + k * 131072, outST + k * 65536, 8, 512, 256);
  }

  prep_mats<<<dim3(1024, 28), dim3(256), 0, stream>>>(md);
  prep_convw<<<dim3(144), dim3(256), 0, stream>>>(w_conv2, w2q);
  r_kernel<<<dim3(2), dim3(256), 0, stream>>>(rois, rbuf);
  convf_kernel<<<dim3(2048), dim3(512), 0, stream>>>(x, w_conv1, b_conv1, w2q, b_conv2, feat2);
  roi_pool_kernel<<<dim3(6144), dim3(256), 0, stream>>>(feat2, rois, pool);
  gemmB_kernel<<<dim3(192), dim3(512), 0, stream>>>(pool, 1024, fc0T, fc0_b, cat, 512, 0, 10);
  emb1_kernel<<<dim3(1536), dim3(256), 0, stream>>>(src_coor, fc0c_w, fc0c_b, emb1);
  gemmB_kernel<<<dim3(192), dim3(512), 0, stream>>>(emb1, 256, fc1cT, fc1c_b, cat, 512, 256, 8);
  gemmB_kernel<<<dim3(192), dim3(512), 0, stream>>>(cat, 512, redT, red_b, obj, 256, 0, 9);
  for (int j = 0; j < 8; j++) {
    internet_kernel<<<dim3(256), dim3(512), 0, stream>>>(j, obj, sbuf, src_coor, out, rbuf, cs,
        selfT, uT, vT, affT, outAT, outST, g_self_b, g_rel_b, g_aff_b, g_out_b);
    agg_kernel<<<dim3(64), dim3(512), 0, stream>>>(j, cs, aggT, agg_b, dec_w, dec_b, sbuf, out);
  }
  (void)in_sizes; (void)n_in; (void)out_size; (void)ws_size;
}

// Round 3
// 1008.220 us; speedup vs baseline: 1.0734x; 1.0734x over previous
//
#include <hip/hip_runtime.h>

// Problem constants
#define BB 64
#define TT 4
#define NOBJ 6
#define RTOT 1536   // B*T*N
#define DD 256

struct MatDesc { const float* src; float* dst; int kshift; int stride; int coff; };
struct MatDescs { MatDesc m[28]; };

#define FMA4(ACC, A4, W4) do { \
  ACC = fmaf((A4).x, (W4).x, ACC); \
  ACC = fmaf((A4).y, (W4).y, ACC); \
  ACC = fmaf((A4).z, (W4).z, ACC); \
  ACC = fmaf((A4).w, (W4).w, ACC); } while(0)

// ---- prep: transpose N=256 weight mats into WT[kq][d][4] layout ----
__global__ void prep_mats(MatDescs md) {
  const MatDesc de = md.m[blockIdx.y];
  int K = 1 << de.kshift;
  int idx = blockIdx.x * 256 + threadIdx.x;
  if (idx >= (256 << de.kshift)) return;
  int d = idx >> de.kshift;
  int kk = idx & (K - 1);
  de.dst[(kk >> 2) * 1024 + d * 4 + (kk & 3)] = de.src[d * de.stride + de.coff + kk];
}

// ---- prep conv2 weights: w2q[((ci*3+ky)*8+coq)*24 + cj*3+kx] ----
__global__ void prep_convw(const float* __restrict__ w2, float* __restrict__ w2q) {
  int i2 = blockIdx.x * 256 + threadIdx.x;
  if (i2 >= 36864) return;
  int kx = i2 % 3, cj = (i2 / 3) & 7, coq = (i2 / 24) & 7, ky = (i2 / 192) % 3, ci = i2 / 576;
  w2q[i2] = w2[((coq * 8 + cj) * 64 + ci) * 9 + ky * 3 + kx];
}

// ---- r = mean_t(((y2-y1)/2 + (x2-x1)/2)/2) ----
__global__ void r_kernel(const float* __restrict__ rois, float* __restrict__ rbuf) {
  int i = blockIdx.x * 256 + threadIdx.x;
  if (i >= BB * NOBJ) return;
  int b = i / NOBJ, n = i % NOBJ;
  float acc = 0.f;
  for (int t = 0; t < TT; t++) {
    const float* rp = rois + ((b * TT + t) * NOBJ + n) * 5;
    acc += (rp[4] - rp[2]) * 0.5f + (rp[3] - rp[1]) * 0.5f;
  }
  rbuf[i] = acc * 0.125f;   // /2 then mean over T=4
}

// ---- fused conv1+conv2 with even/odd split LDS layouts (bank-conflict-free) ----
// x (256,3,128,128) -> relu conv1 s2 -> relu conv2 s2 -> feat2 (256,64,32,32)
// Per block: image n, feat2 rows oy0..oy0+3.
// xs:  [ci][19 rows][ e_x:0..67 | o_x:68..135 ]  (e_x[c]=x[2c], o_x[c]=x[2c+1])
// f1c: [cl][9 rows][ e:0..35 | o:36..71 ]        (e[c]=f1[2c], o[c]=f1[2c+1])
__global__ __launch_bounds__(512, 6) void convf_kernel(const float* __restrict__ x,
                                                       const float* __restrict__ w1,
                                                       const float* __restrict__ b1,
                                                       const float* __restrict__ w2q,
                                                       const float* __restrict__ b2,
                                                       float* __restrict__ feat2) {
  __shared__ __align__(16) float xs[3 * 19 * 136];   // 31.0 KB
  __shared__ __align__(16) float f1c[4 * 9 * 72];    // 10.4 KB
  __shared__ float w1s[1728];
  __shared__ float b1s[64];
  int bx = blockIdx.x;
  int n = bx >> 3;
  int oy0 = (bx & 7) * 4;
  int f1base = 2 * oy0;   // feat1 rows f1base..f1base+8 (row>=64 is zero pad)
  int xbase = 4 * oy0;    // x rows xbase..xbase+18 (row>=128 zero)
  int tid = threadIdx.x;
  for (int i = tid; i < 1728; i += 512) w1s[i] = w1[i];
  if (tid < 64) b1s[tid] = b1[tid];
  if (tid < 36) f1c[tid * 72 + 32] = 0.f;   // e[32] = f1 col 64 pad, written once
  for (int i = tid; i < 3 * 19 * 33; i += 512) {
    int c4 = i % 33;               // 0..32 (c4==32 writes zeros for e[64..65], o[64..65])
    int row = (i / 33) % 19;
    int ci = i / (33 * 19);
    int gr = xbase + row;
    float4 v = {0.f, 0.f, 0.f, 0.f};
    if (gr < 128 && c4 < 32)
      v = *(const float4*)(x + ((n * 3 + ci) * 128 + gr) * 128 + c4 * 4);
    float* bp = &xs[(ci * 19 + row) * 136];
    *(float2*)&bp[2 * c4]      = make_float2(v.x, v.z);   // e_x[2c4], e_x[2c4+1]
    *(float2*)&bp[68 + 2 * c4] = make_float2(v.y, v.w);   // o_x[2c4], o_x[2c4+1]
  }
  int coq = __builtin_amdgcn_readfirstlane(tid >> 6);   // wave -> co octet
  int l = tid & 63;
  int oc = l & 31;        // output col
  int rp = l >> 5;        // row-pair 0..1 (rows oy0 + rp*2 + rr)
  float acc[8][2] = {};
  for (int cc = 0; cc < 16; cc++) {
    __syncthreads();
    // conv1 phase: compute f1 channels cc*4..cc*4+3 into f1c (e/o split)
    for (int it = tid; it < 576; it += 512) {
      int c4 = it & 15;
      int r9 = (it >> 4) % 9;
      int cl = it / 144;
      int co1 = cc * 4 + cl;
      float u0 = 0.f, u1 = 0.f, u2 = 0.f, u3 = 0.f;
      if (f1base + r9 < 64) {
        const float* wp = &w1s[co1 * 27];
        #pragma unroll
        for (int ci = 0; ci < 3; ci++) {
          #pragma unroll
          for (int ky = 0; ky < 3; ky++) {
            const float* bp = &xs[(ci * 19 + 2 * r9 + ky) * 136];
            float4 e4 = *(const float4*)&bp[4 * c4];        // e_x[4c4..4c4+3]
            float e5 = bp[4 * c4 + 4];                       // e_x[4c4+4]
            float4 q4 = *(const float4*)&bp[68 + 4 * c4];    // o_x[4c4..4c4+3]
            float w0 = wp[ci * 9 + ky * 3 + 0];
            float w1v = wp[ci * 9 + ky * 3 + 1];
            float w2v = wp[ci * 9 + ky * 3 + 2];
            u0 = fmaf(e4.x, w0, u0); u0 = fmaf(q4.x, w1v, u0); u0 = fmaf(e4.y, w2v, u0);
            u1 = fmaf(e4.y, w0, u1); u1 = fmaf(q4.y, w1v, u1); u1 = fmaf(e4.z, w2v, u1);
            u2 = fmaf(e4.z, w0, u2); u2 = fmaf(q4.z, w1v, u2); u2 = fmaf(e4.w, w2v, u2);
            u3 = fmaf(e4.w, w0, u3); u3 = fmaf(q4.w, w1v, u3); u3 = fmaf(e5,   w2v, u3);
          }
        }
        float bb = b1s[co1];
        u0 = fmaxf(u0 + bb, 0.f); u1 = fmaxf(u1 + bb, 0.f);
        u2 = fmaxf(u2 + bb, 0.f); u3 = fmaxf(u3 + bb, 0.f);
      }
      float* fp = &f1c[(cl * 9 + r9) * 72];
      *(float2*)&fp[2 * c4]      = make_float2(u0, u2);   // e[2c4], e[2c4+1]
      *(float2*)&fp[36 + 2 * c4] = make_float2(u1, u3);   // o[2c4], o[2c4+1]
    }
    __syncthreads();
    // conv2 accumulate: out col oc needs f1 cols 2oc,2oc+1,2oc+2 = e[oc], o[oc], e[oc+1]
    #pragma unroll
    for (int cl = 0; cl < 4; cl++) {
      int ci = cc * 4 + cl;
      #pragma unroll
      for (int ky = 0; ky < 3; ky++) {
        const float* wp = &w2q[((ci * 3 + ky) * 8 + coq) * 24];
        #pragma unroll
        for (int rr = 0; rr < 2; rr++) {
          int rl = 2 * (rp * 2 + rr) + ky;
          const float* fp = &f1c[(cl * 9 + rl) * 72];
          float e0 = fp[oc];
          float e1 = fp[oc + 1];
          float q0 = fp[36 + oc];
          #pragma unroll
          for (int cj = 0; cj < 8; cj++) {
            float w0 = wp[cj * 3], w1v = wp[cj * 3 + 1], w2v = wp[cj * 3 + 2];
            acc[cj][rr] = fmaf(e0, w0, acc[cj][rr]);
            acc[cj][rr] = fmaf(q0, w1v, acc[cj][rr]);
            acc[cj][rr] = fmaf(e1, w2v, acc[cj][rr]);
          }
        }
      }
    }
  }
  #pragma unroll
  for (int rr = 0; rr < 2; rr++) {
    int oy = oy0 + rp * 2 + rr;
    #pragma unroll
    for (int cj = 0; cj < 8; cj++) {
      float v = fmaxf(acc[cj][rr] + b2[coq * 8 + cj], 0.f);
      feat2[((n * 64 + coq * 8 + cj) * 32 + oy) * 32 + oc] = v;
    }
  }
}

// ---- ROI align: feat2 (256,64,32,32) + rois(1536,5) -> pool (1536, 64*4*4) c-major ----
__global__ void roi_pool_kernel(const float* __restrict__ feat2, const float* __restrict__ rois,
                                float* __restrict__ pool) {
  int o = blockIdx.x * 256 + threadIdx.x;
  if (o >= RTOT * 1024) return;
  int px = o & 3, py = (o >> 2) & 3, c = (o >> 4) & 63, r = o >> 10;
  const float* rp = rois + r * 5;
  int bi = (int)rp[0];
  float x1 = rp[1] * 0.25f, y1 = rp[2] * 0.25f, x2 = rp[3] * 0.25f, y2 = rp[4] * 0.25f;
  float bw = fmaxf(x2 - x1, 1.0f) * 0.25f;
  float bh = fmaxf(y2 - y1, 1.0f) * 0.25f;
  float sx = x1 + bw * (px + 0.5f);
  float sy = y1 + bh * (py + 0.5f);
  float x0f = fminf(fmaxf(floorf(sx), 0.f), 31.f);
  float y0f = fminf(fmaxf(floorf(sy), 0.f), 31.f);
  float lx = fminf(fmaxf(sx - x0f, 0.f), 1.f);
  float ly = fminf(fmaxf(sy - y0f, 0.f), 1.f);
  int ix0 = (int)x0f, iy0 = (int)y0f;
  int ix1 = min(ix0 + 1, 31), iy1 = min(iy0 + 1, 31);
  const float* f = feat2 + (bi * 64 + c) * 1024;
  float v00 = f[iy0 * 32 + ix0], v01 = f[iy0 * 32 + ix1];
  float v10 = f[iy1 * 32 + ix0], v11 = f[iy1 * 32 + ix1];
  pool[o] = v00 * (1 - ly) * (1 - lx) + v01 * (1 - ly) * lx + v10 * ly * (1 - lx) + v11 * ly * lx;
}

// ---- emb1: (1536,2)@(256,2)^T + b, relu ----
__global__ void emb1_kernel(const float* __restrict__ coor, const float* __restrict__ w,
                            const float* __restrict__ b, float* __restrict__ out) {
  int o = blockIdx.x * 256 + threadIdx.x;
  if (o >= RTOT * DD) return;
  int c = o & 255, r = o >> 8;
  float v = coor[r * 2] * w[c * 2] + coor[r * 2 + 1] * w[c * 2 + 1] + b[c];
  out[o] = fmaxf(v, 0.f);
}

// ---- generic broadcast-row GEMM + bias + relu ----
__global__ __launch_bounds__(512) void gemmB_kernel(const float* __restrict__ A, int lda,
                                                    const float* __restrict__ WT,
                                                    const float* __restrict__ bias,
                                                    float* __restrict__ C, int ldc, int coff,
                                                    int kshift) {
  __shared__ __align__(16) float As[8 * 1024];
  int K = 1 << kshift;
  int tid = threadIdx.x;
  int r0 = blockIdx.x * 8;
  for (int idx = tid; idx < 8 * K; idx += 512)
    As[idx] = A[(r0 + (idx >> kshift)) * lda + (idx & (K - 1))];
  __syncthreads();
  int d = tid & 255;
  int half = __builtin_amdgcn_readfirstlane(tid >> 8);
  float acc[4] = {};
  const float* asb = As + half * 4 * K;
  for (int kq = 0; kq < (K >> 2); kq++) {
    float4 wv = *(const float4*)(WT + kq * 1024 + d * 4);
    #pragma unroll
    for (int rr = 0; rr < 4; rr++) {
      float4 a4 = *(const float4*)(asb + rr * K + kq * 4);
      FMA4(acc[rr], a4, wv);
    }
  }
  float bv = bias[d];
  #pragma unroll
  for (int rr = 0; rr < 4; rr++)
    C[(r0 + half * 4 + rr) * ldc + coff + d] = fmaxf(acc[rr] + bv, 0.f);
}

// ---- internet kernel: one block per (b,k); k=3 blocks also dec() the previous rollout ----
__global__ __launch_bounds__(512) void internet_kernel(
    int j, const float* __restrict__ obj, const float* __restrict__ sbuf,
    const float* __restrict__ src_coor, float* __restrict__ dout,
    const float* __restrict__ rbuf, float* __restrict__ cs,
    const float* __restrict__ selfT, const float* __restrict__ uT,
    const float* __restrict__ vT, const float* __restrict__ affT,
    const float* __restrict__ outAT, const float* __restrict__ outST,
    const float* __restrict__ self_b, const float* __restrict__ rel_b,
    const float* __restrict__ aff_b, const float* __restrict__ out_b,
    const float* __restrict__ decw, const float* __restrict__ decb) {
  __shared__ __align__(16) float s_lds[6 * 256];
  __shared__ __align__(16) float v_lds[6 * 256];
  __shared__ __align__(16) float h_lds[6 * 256];
  __shared__ __align__(16) float a_lds[6 * 256];
  __shared__ float coor_lds[12], r_lds[6], mw[6][8];
  int bx = blockIdx.x;
  int xcd = bx & 7;
  int k = __builtin_amdgcn_readfirstlane(xcd >> 1);           // XCD-swizzle: one k per XCD-pair
  int b = __builtin_amdgcn_readfirstlane(((xcd & 1) << 5) + (bx >> 3));
  int sl = j + k;
  int tid = threadIdx.x;
  const float* srow = (sl < 4) ? (obj + (b * 4 + sl) * 6 * 256)
                               : (sbuf + ((sl - 4) * 64 + b) * 6 * 256);
  for (int idx = tid; idx < 1536; idx += 512) s_lds[idx] = srow[idx];
  if (tid < 6) r_lds[tid] = rbuf[b * 6 + tid];
  bool dodec = (k == 3) && (j >= 1);   // s_lds == sn[j-1][b]; dec it here
  if (!dodec && tid < 12) {
    int i = tid >> 1, c = tid & 1;
    coor_lds[tid] = (sl < 4) ? src_coor[((b * 4 + sl) * 6 + i) * 2 + c]
                             : dout[((b * 8 + (sl - 4)) * 6 + i) * 4 + 2 + c];
  }
  __syncthreads();
  if (dodec && tid < 384) {
    int lane16 = tid & 15;
    int p = tid >> 4;      // 0..23
    int i = p >> 2, o = p & 3;
    float a2 = 0.f;
    #pragma unroll
    for (int m = 0; m < 16; m++) {
      int dd = lane16 + m * 16;
      a2 = fmaf(s_lds[i * 256 + dd], decw[o * 256 + dd], a2);
    }
    a2 += __shfl_down(a2, 8, 16);
    a2 += __shfl_down(a2, 4, 16);
    a2 += __shfl_down(a2, 2, 16);
    a2 += __shfl_down(a2, 1, 16);
    if (lane16 == 0) {
      float val = a2 + decb[o];
      dout[((b * 8 + (j - 1)) * 6 + i) * 4 + o] = val;
      if (o >= 2) coor_lds[i * 2 + (o - 2)] = val;
    }
  }
  __syncthreads();
  if (tid < 36) {
    int i = tid / 6, jj = tid % 6;
    float dx = coor_lds[i * 2] - coor_lds[jj * 2];
    float dy = coor_lds[i * 2 + 1] - coor_lds[jj * 2 + 1];
    float dist = sqrtf(dx * dx + dy * dy);
    mw[i][jj] = (i != jj && dist <= r_lds[i] + r_lds[jj]) ? 1.f : 0.f;
  }
  int d = tid & 255;
  int half = __builtin_amdgcn_readfirstlane(tid >> 8);
  const float* sT = selfT + k * 65536;
  const float* uTk = uT + k * 65536;
  const float* vTk = vT + k * 65536;
  const float* sbase = s_lds + half * 3 * 256;
  float as[3] = {}, au[3] = {}, av[3] = {};
  for (int kq = 0; kq < 64; kq++) {
    float4 ws = *(const float4*)(sT + kq * 1024 + d * 4);
    float4 wu = *(const float4*)(uTk + kq * 1024 + d * 4);
    float4 wv = *(const float4*)(vTk + kq * 1024 + d * 4);
    #pragma unroll
    for (int rr = 0; rr < 3; rr++) {
      float4 a4 = *(const float4*)(sbase + rr * 256 + kq * 4);
      FMA4(as[rr], a4, ws);
      FMA4(au[rr], a4, wu);
      FMA4(av[rr], a4, wv);
    }
  }
  #pragma unroll
  for (int rr = 0; rr < 3; rr++) v_lds[(half * 3 + rr) * 256 + d] = av[rr];
  __syncthreads();
  float sbv = self_b[k * 256 + d];
  float rbv = rel_b[k * 256 + d];
  #pragma unroll
  for (int rr = 0; rr < 3; rr++) {
    int i = half * 3 + rr;
    float cnt = mw[i][0] + mw[i][1] + mw[i][2] + mw[i][3] + mw[i][4] + mw[i][5];
    float relsum = cnt * (au[rr] + rbv);
    #pragma unroll
    for (int jj = 0; jj < 6; jj++)
      relsum = fmaf(mw[i][jj], v_lds[jj * 256 + d], relsum);
    h_lds[i * 256 + d] = as[rr] + sbv + relsum;
  }
  __syncthreads();
  const float* aT = affT + k * 65536;
  const float* hbase = h_lds + half * 3 * 256;
  float aa[3] = {};
  for (int kq = 0; kq < 64; kq++) {
    float4 wv = *(const float4*)(aT + kq * 1024 + d * 4);
    #pragma unroll
    for (int rr = 0; rr < 3; rr++) {
      float4 a4 = *(const float4*)(hbase + rr * 256 + kq * 4);
      FMA4(aa[rr], a4, wv);
    }
  }
  float abv = aff_b[k * 256 + d];
  #pragma unroll
  for (int rr = 0; rr < 3; rr++)
    a_lds[(half * 3 + rr) * 256 + d] = fmaxf(aa[rr] + abv, 0.f);
  __syncthreads();
  const float* oaT = outAT + k * 65536;
  const float* osT = outST + k * 65536;
  const float* abase = a_lds + half * 3 * 256;
  float ao[3] = {};
  for (int kq = 0; kq < 64; kq++) {
    float4 wa = *(const float4*)(oaT + kq * 1024 + d * 4);
    float4 wsv = *(const float4*)(osT + kq * 1024 + d * 4);
    #pragma unroll
    for (int rr = 0; rr < 3; rr++) {
      float4 a4 = *(const float4*)(abase + rr * 256 + kq * 4);
      float4 s4 = *(const float4*)(sbase + rr * 256 + kq * 4);
      FMA4(ao[rr], a4, wa);
      FMA4(ao[rr], s4, wsv);
    }
  }
  float obv = out_b[k * 256 + d];
  #pragma unroll
  for (int rr = 0; rr < 3; rr++)
    cs[(b * 6 + half * 3 + rr) * 1024 + k * 256 + d] = fmaxf(ao[rr] + obv, 0.f);
}

// ---- agg (d-sliced 4-wide): block (b, dq) computes sn[b][:, dq*64..+63], no relu ----
__global__ __launch_bounds__(512) void agg4_kernel(int j, const float* __restrict__ cs,
                                                   const float* __restrict__ aggT,
                                                   const float* __restrict__ agg_b,
                                                   float* __restrict__ sbuf) {
  __shared__ __align__(16) float cs_lds[6 * 1024];
  int bx = blockIdx.x;
  int dq = bx & 3;          // XCD x serves slice x&3 (round-robin dispatch)
  int b = bx >> 2;
  int tid = threadIdx.x;
  for (int idx = tid; idx < 6144; idx += 512) cs_lds[idx] = cs[b * 6144 + idx];
  __syncthreads();
  int d = tid & 63;
  int i = tid >> 6;         // 0..7, active < 6
  if (i < 6) {
    float acc = 0.f;
    const float* wp = aggT + (dq * 64 + d) * 4;
    const float* ap = cs_lds + i * 1024;
    for (int kq = 0; kq < 256; kq++) {
      float4 wv = *(const float4*)(wp + kq * 1024);
      float4 a4 = *(const float4*)(ap + kq * 4);
      FMA4(acc, a4, wv);
    }
    sbuf[((j * 64 + b) * 6 + i) * 256 + dq * 64 + d] = acc + agg_b[dq * 64 + d];
  }
}

// ---- final dec for rollout 7 ----
__global__ void dec_last(const float* __restrict__ sbuf, const float* __restrict__ decw,
                         const float* __restrict__ decb, float* __restrict__ dout) {
  int b = blockIdx.x;
  int tid = threadIdx.x;   // 384
  int lane16 = tid & 15;
  int p = tid >> 4;        // 0..23
  int i = p >> 2, o = p & 3;
  const float* sp = sbuf + ((size_t)(7 * 64 + b) * 6 + i) * 256;
  float a2 = 0.f;
  #pragma unroll
  for (int m = 0; m < 16; m++) {
    int dd = lane16 + m * 16;
    a2 = fmaf(sp[dd], decw[o * 256 + dd], a2);
  }
  a2 += __shfl_down(a2, 8, 16);
  a2 += __shfl_down(a2, 4, 16);
  a2 += __shfl_down(a2, 2, 16);
  a2 += __shfl_down(a2, 1, 16);
  if (lane16 == 0) dout[((b * 8 + 7) * 6 + i) * 4 + o] = a2 + decb[o];
}

extern "C" void kernel_launch(void* const* d_in, const int* in_sizes, int n_in,
                              void* d_out, int out_size, void* d_ws, size_t ws_size,
                              hipStream_t stream) {
  const float* x        = (const float*)d_in[0];
  const float* rois     = (const float*)d_in[1];
  const float* src_coor = (const float*)d_in[2];
  const float* w_conv1  = (const float*)d_in[3];
  const float* b_conv1  = (const float*)d_in[4];
  const float* w_conv2  = (const float*)d_in[5];
  const float* b_conv2  = (const float*)d_in[6];
  const float* fc0_w    = (const float*)d_in[7];
  const float* fc0_b    = (const float*)d_in[8];
  const float* fc0c_w   = (const float*)d_in[9];
  const float* fc0c_b   = (const float*)d_in[10];
  const float* fc1c_w   = (const float*)d_in[11];
  const float* fc1c_b   = (const float*)d_in[12];
  const float* red_w    = (const float*)d_in[13];
  const float* red_b    = (const float*)d_in[14];
  const float* g_self_w = (const float*)d_in[15];
  const float* g_self_b = (const float*)d_in[16];
  const float* g_rel_w  = (const float*)d_in[17];
  const float* g_rel_b  = (const float*)d_in[18];
  const float* g_aff_w  = (const float*)d_in[19];
  const float* g_aff_b  = (const float*)d_in[20];
  const float* g_out_w  = (const float*)d_in[21];
  const float* g_out_b  = (const float*)d_in[22];
  const float* agg_w    = (const float*)d_in[23];
  const float* agg_b    = (const float*)d_in[24];
  const float* dec_w    = (const float*)d_in[25];
  const float* dec_b    = (const float*)d_in[26];
  float* out = (float*)d_out;

  float* ws = (float*)d_ws;
  size_t off = 0;
  auto alloc = [&](size_t nf) { float* p = ws + off; off += (nf + 63) & ~(size_t)63; return p; };
  float* feat2 = alloc(16777216);   // (256,64,32,32)
  float* pool  = alloc(1572864);    // (1536,1024)
  float* cat   = alloc(786432);     // (1536,512)
  float* emb1  = alloc(393216);     // (1536,256)
  float* obj   = alloc(393216);     // (B,T,N,256) = state slots 0..3
  float* sbuf  = alloc(786432);     // (8,B,N,256) = state slots 4..11
  float* cs    = alloc(393216);     // (B,N,1024)
  float* rbuf  = alloc(384);
  float* fc0T  = alloc(262144);
  float* fc1cT = alloc(65536);
  float* redT  = alloc(131072);
  float* aggT  = alloc(262144);
  float* selfT = alloc(262144);
  float* uT    = alloc(262144);
  float* vT    = alloc(262144);
  float* affT  = alloc(262144);
  float* outAT = alloc(262144);
  float* outST = alloc(262144);
  float* w2q   = alloc(36864);

  MatDescs md;
  int mi = 0;
  auto add = [&](const float* s, float* dstp, int ksh, int stride, int coff) {
    md.m[mi].src = s; md.m[mi].dst = dstp; md.m[mi].kshift = ksh;
    md.m[mi].stride = stride; md.m[mi].coff = coff; mi++;
  };
  add(fc0_w,  fc0T,  10, 1024, 0);
  add(fc1c_w, fc1cT, 8,  256,  0);
  add(red_w,  redT,  9,  512,  0);
  add(agg_w,  aggT,  10, 1024, 0);
  for (int k = 0; k < 4; k++) {
    add(g_self_w + k * 65536,  selfT + k * 65536, 8, 256, 0);
    add(g_rel_w  + k * 131072, uT    + k * 65536, 8, 512, 0);
    add(g_rel_w  + k * 131072, vT    + k * 65536, 8, 512, 256);
    add(g_aff_w  + k * 65536,  affT  + k * 65536, 8, 256, 0);
    add(g_out_w  + k * 131072, outAT + k * 65536, 8, 512, 0);
    add(g_out_w  + k * 131072, outST + k * 65536, 8, 512, 256);
  }

  prep_mats<<<dim3(1024, 28), dim3(256), 0, stream>>>(md);
  prep_convw<<<dim3(144), dim3(256), 0, stream>>>(w_conv2, w2q);
  r_kernel<<<dim3(2), dim3(256), 0, stream>>>(rois, rbuf);
  convf_kernel<<<dim3(2048), dim3(512), 0, stream>>>(x, w_conv1, b_conv1, w2q, b_conv2, feat2);
  roi_pool_kernel<<<dim3(6144), dim3(256), 0, stream>>>(feat2, rois, pool);
  gemmB_kernel<<<dim3(192), dim3(512), 0, stream>>>(pool, 1024, fc0T, fc0_b, cat, 512, 0, 10);
  emb1_kernel<<<dim3(1536), dim3(256), 0, stream>>>(src_coor, fc0c_w, fc0c_b, emb1);
  gemmB_kernel<<<dim3(192), dim3(512), 0, stream>>>(emb1, 256, fc1cT, fc1c_b, cat, 512, 256, 8);
  gemmB_kernel<<<dim3(192), dim3(512), 0, stream>>>(cat, 512, redT, red_b, obj, 256, 0, 9);
  for (int j = 0; j < 8; j++) {
    internet_kernel<<<dim3(256), dim3(512), 0, stream>>>(j, obj, sbuf, src_coor, out, rbuf, cs,
        selfT, uT, vT, affT, outAT, outST, g_self_b, g_rel_b, g_aff_b, g_out_b, dec_w, dec_b);
    agg4_kernel<<<dim3(256), dim3(512), 0, stream>>>(j, cs, aggT, agg_b, sbuf);
  }
  dec_last<<<dim3(64), dim3(384), 0, stream>>>(sbuf, dec_w, dec_b, out);
  (void)in_sizes; (void)n_in; (void)out_size; (void)ws_size;
}

// Round 4
// 879.907 us; speedup vs baseline: 1.2299x; 1.1458x over previous
//
#include <hip/hip_runtime.h>

// Problem constants
#define BB 64
#define TT 4
#define NOBJ 6
#define RTOT 1536   // B*T*N
#define DD 256

typedef unsigned short ushort_t;
typedef __attribute__((ext_vector_type(8))) short short8_t;   // 8 bf16 (4 VGPRs)
typedef __attribute__((ext_vector_type(4))) float f32x4;

struct MatDesc { const float* src; float* dst; int kshift; int stride; int coff; };
struct MatDescs { MatDesc m[28]; };

#define FMA4(ACC, A4, W4) do { \
  ACC = fmaf((A4).x, (W4).x, ACC); \
  ACC = fmaf((A4).y, (W4).y, ACC); \
  ACC = fmaf((A4).z, (W4).z, ACC); \
  ACC = fmaf((A4).w, (W4).w, ACC); } while(0)

// ---- prep: transpose N=256 weight mats into WT[kq][d][4] layout ----
__global__ void prep_mats(MatDescs md) {
  const MatDesc de = md.m[blockIdx.y];
  int K = 1 << de.kshift;
  int idx = blockIdx.x * 256 + threadIdx.x;
  if (idx >= (256 << de.kshift)) return;
  int d = idx >> de.kshift;
  int kk = idx & (K - 1);
  de.dst[(kk >> 2) * 1024 + d * 4 + (kk & 3)] = de.src[d * de.stride + de.coff + kk];
}

// ---- prep conv weights ----
// w1p[tap*64 + co] = w1[co][tap]  (tap = (ci*3+ky)*3+kx)
// w2f planes (bf16 hi/lo): idx = (((t*2+q)*4 + nt)*64 + lane)*8 + j
//   value = w2[co = nt*16 + (lane&15)][ci = q*32 + (lane>>4)*8 + j][t]
__global__ void prep_convw2(const float* __restrict__ w1, const float* __restrict__ w2,
                            float* __restrict__ w1p, ushort_t* __restrict__ w2fh,
                            ushort_t* __restrict__ w2fl) {
  int idx = blockIdx.x * 256 + threadIdx.x;
  if (idx < 1728) {
    int co = idx & 63, tap = idx >> 6;
    w1p[idx] = w1[co * 27 + tap];
  }
  int i2 = idx - 2048;
  if (i2 >= 0 && i2 < 36864) {
    int j = i2 & 7, lane = (i2 >> 3) & 63, nt = (i2 >> 9) & 3, q = (i2 >> 11) & 1, t = i2 >> 12;
    int co = nt * 16 + (lane & 15);
    int ci = q * 32 + ((lane >> 4) << 3) + j;
    float v = w2[(co * 64 + ci) * 9 + t];
    unsigned int b = __float_as_uint(v);
    ushort_t hs = (ushort_t)(b >> 16);
    float hf = __uint_as_float(b & 0xFFFF0000u);
    ushort_t ls = (ushort_t)(__float_as_uint(v - hf) >> 16);
    w2fh[i2] = hs; w2fl[i2] = ls;
  }
}

// ---- r = mean_t(((y2-y1)/2 + (x2-x1)/2)/2) ----
__global__ void r_kernel(const float* __restrict__ rois, float* __restrict__ rbuf) {
  int i = blockIdx.x * 256 + threadIdx.x;
  if (i >= BB * NOBJ) return;
  int b = i / NOBJ, n = i % NOBJ;
  float acc = 0.f;
  for (int t = 0; t < TT; t++) {
    const float* rp = rois + ((b * TT + t) * NOBJ + n) * 5;
    acc += (rp[4] - rp[2]) * 0.5f + (rp[3] - rp[1]) * 0.5f;
  }
  rbuf[i] = acc * 0.125f;
}

// ---- fused conv1(fp32 vector) + conv2(split-bf16 MFMA) ----
// Block = (n, band 0..15, h 0..1): output rows 2*band..2*band+1, cols h*16..h*16+15, 64 ch.
// f1 rows 4*band..4*band+4 (5), local cols 0..32 (global h*32..h*32+32), stored hi/lo bf16
// in [row][col][ci] (ci contiguous) for MFMA A-fragments.
__global__ __launch_bounds__(512, 4) void convmf_kernel(const float* __restrict__ x,
                                                        const float* __restrict__ w1p,
                                                        const float* __restrict__ b1,
                                                        const ushort_t* __restrict__ w2fh,
                                                        const ushort_t* __restrict__ w2fl,
                                                        const float* __restrict__ b2,
                                                        float* __restrict__ feat2) {
  __shared__ __align__(16) float xs[3 * 11 * 72];          // 9.5 KB
  __shared__ __align__(16) ushort_t f1h[5 * 34 * 72];      // 24.5 KB
  __shared__ __align__(16) ushort_t f1l[5 * 34 * 72];      // 24.5 KB
  int bx = blockIdx.x;
  int h = bx & 1;
  int band = (bx >> 1) & 15;
  int n = bx >> 5;
  int tid = threadIdx.x;
  int wave = __builtin_amdgcn_readfirstlane(tid >> 6);
  int lane = tid & 63;

  // ---- stage x slab: rows 8*band..+10, local cols 0..67 (global h*64 + c), rest 0
  for (int i = tid; i < 3 * 11 * 72; i += 512) {
    int c = i % 72;
    int row = (i / 72) % 11;
    int ci = i / (72 * 11);
    int gr = 8 * band + row;
    int gc = h * 64 + c;
    float v = 0.f;
    if (gr < 128 && gc < 128 && c < 68) v = x[((n * 3 + ci) * 128 + gr) * 128 + gc];
    xs[(ci * 11 + row) * 72 + c] = v;
  }
  __syncthreads();

  // ---- conv1: wave -> f1 channel octet (chb = wave*8); items: (r0,cp0) + row-4/col-32 extras
  int chb = wave * 8;
  int r0 = lane >> 4;          // 0..3
  int cp0 = lane & 15;         // col pair -> cols 2cp0, 2cp0+1
  int rB, xB;
  if (lane < 16) { rB = 4; xB = 4 * cp0; }
  else { int rr = lane - 16; rB = (rr < 5) ? rr : 0; xB = 64; }
  float a0[2][8] = {}; float aB[2][8] = {};
  for (int ci = 0; ci < 3; ci++) {
    #pragma unroll
    for (int ky = 0; ky < 3; ky++) {
      const float* wp = w1p + ((ci * 3 + ky) * 3) * 64 + chb;   // uniform -> s_loads
      float wv[3][8];
      #pragma unroll
      for (int kx = 0; kx < 3; kx++)
        #pragma unroll
        for (int j = 0; j < 8; j++) wv[kx][j] = wp[kx * 64 + j];
      const float* x0 = &xs[(ci * 11 + 2 * r0 + ky) * 72 + 4 * cp0];
      float4 e4 = *(const float4*)x0; float e5 = x0[4];
      float xv[5] = {e4.x, e4.y, e4.z, e4.w, e5};
      #pragma unroll
      for (int c = 0; c < 2; c++)
        #pragma unroll
        for (int kx = 0; kx < 3; kx++) {
          float xx = xv[2 * c + kx];
          #pragma unroll
          for (int j = 0; j < 8; j++) a0[c][j] = fmaf(xx, wv[kx][j], a0[c][j]);
        }
      const float* x1 = &xs[(ci * 11 + 2 * rB + ky) * 72 + xB];
      float4 f4 = *(const float4*)x1; float f5 = x1[4];
      float yv[5] = {f4.x, f4.y, f4.z, f4.w, f5};
      #pragma unroll
      for (int c = 0; c < 2; c++)
        #pragma unroll
        for (int kx = 0; kx < 3; kx++) {
          float xx = yv[2 * c + kx];
          #pragma unroll
          for (int j = 0; j < 8; j++) aB[c][j] = fmaf(xx, wv[kx][j], aB[c][j]);
        }
    }
  }
  float bb[8];
  #pragma unroll
  for (int j = 0; j < 8; j++) bb[j] = b1[chb + j];
  auto storecol = [&](int row, int col, const float* a, bool ok) {
    short8_t hv, lv;
    #pragma unroll
    for (int j = 0; j < 8; j++) {
      float v = ok ? fmaxf(a[j] + bb[j], 0.f) : 0.f;
      unsigned int bits = __float_as_uint(v);
      hv[j] = (short)(bits >> 16);
      float hf = __uint_as_float(bits & 0xFFFF0000u);
      lv[j] = (short)(__float_as_uint(v - hf) >> 16);
    }
    int base = (row * 34 + col) * 72 + chb;
    *(short8_t*)&f1h[base] = hv;
    *(short8_t*)&f1l[base] = lv;
  };
  storecol(r0, 2 * cp0,     a0[0], true);
  storecol(r0, 2 * cp0 + 1, a0[1], true);
  if (lane < 16) {
    bool ok4 = (4 * band + 4) < 64;
    storecol(4, 2 * cp0,     aB[0], ok4);
    storecol(4, 2 * cp0 + 1, aB[1], ok4);
  } else if (lane < 21) {
    int rr = lane - 16;
    bool okc = (h == 0) && ((4 * band + rr) < 64);
    storecol(rr, 32, aB[0], okc);
  }
  __syncthreads();

  // ---- conv2 via MFMA: wave = (mg = wave>>2, nt = wave&3); tile M = 16 px (ox local),
  // N = 16 co (nt*16+), K = 64 ci in 2 chunks, 9 taps, 3-term bf16 split.
  int nt = wave & 3, mg = wave >> 2;
  f32x4 acc = {0.f, 0.f, 0.f, 0.f};
  #pragma unroll
  for (int t = 0; t < 9; t++) {
    int ky = t / 3, kx = t % 3;
    int col = 2 * (lane & 15) + kx;
    int row = 2 * mg + ky;
    int abase = (row * 34 + col) * 72 + ((lane >> 4) << 3);
    #pragma unroll
    for (int q = 0; q < 2; q++) {
      int widx = (((t * 2 + q) * 4 + nt) * 64 + lane) * 8;
      short8_t Bh = *(const short8_t*)(w2fh + widx);
      short8_t Bl = *(const short8_t*)(w2fl + widx);
      short8_t Ah = *(const short8_t*)&f1h[abase + q * 32];
      short8_t Al = *(const short8_t*)&f1l[abase + q * 32];
      acc = __builtin_amdgcn_mfma_f32_16x16x32_bf16(Ah, Bh, acc, 0, 0, 0);
      acc = __builtin_amdgcn_mfma_f32_16x16x32_bf16(Ah, Bl, acc, 0, 0, 0);
      acc = __builtin_amdgcn_mfma_f32_16x16x32_bf16(Al, Bh, acc, 0, 0, 0);
    }
  }
  int co = nt * 16 + (lane & 15);
  int oy = band * 2 + mg;
  int ox = h * 16 + ((lane >> 4) << 2);
  float bv = b2[co];
  float4 o;
  o.x = fmaxf(acc[0] + bv, 0.f);
  o.y = fmaxf(acc[1] + bv, 0.f);
  o.z = fmaxf(acc[2] + bv, 0.f);
  o.w = fmaxf(acc[3] + bv, 0.f);
  *(float4*)&feat2[((n * 64 + co) * 32 + oy) * 32 + ox] = o;
}

// ---- ROI align: feat2 (256,64,32,32) + rois(1536,5) -> pool (1536, 64*4*4) c-major ----
__global__ void roi_pool_kernel(const float* __restrict__ feat2, const float* __restrict__ rois,
                                float* __restrict__ pool) {
  int o = blockIdx.x * 256 + threadIdx.x;
  if (o >= RTOT * 1024) return;
  int px = o & 3, py = (o >> 2) & 3, c = (o >> 4) & 63, r = o >> 10;
  const float* rp = rois + r * 5;
  int bi = (int)rp[0];
  float x1 = rp[1] * 0.25f, y1 = rp[2] * 0.25f, x2 = rp[3] * 0.25f, y2 = rp[4] * 0.25f;
  float bw = fmaxf(x2 - x1, 1.0f) * 0.25f;
  float bh = fmaxf(y2 - y1, 1.0f) * 0.25f;
  float sx = x1 + bw * (px + 0.5f);
  float sy = y1 + bh * (py + 0.5f);
  float x0f = fminf(fmaxf(floorf(sx), 0.f), 31.f);
  float y0f = fminf(fmaxf(floorf(sy), 0.f), 31.f);
  float lx = fminf(fmaxf(sx - x0f, 0.f), 1.f);
  float ly = fminf(fmaxf(sy - y0f, 0.f), 1.f);
  int ix0 = (int)x0f, iy0 = (int)y0f;
  int ix1 = min(ix0 + 1, 31), iy1 = min(iy0 + 1, 31);
  const float* f = feat2 + (bi * 64 + c) * 1024;
  float v00 = f[iy0 * 32 + ix0], v01 = f[iy0 * 32 + ix1];
  float v10 = f[iy1 * 32 + ix0], v11 = f[iy1 * 32 + ix1];
  pool[o] = v00 * (1 - ly) * (1 - lx) + v01 * (1 - ly) * lx + v10 * ly * (1 - lx) + v11 * ly * lx;
}

// ---- emb1: (1536,2)@(256,2)^T + b, relu ----
__global__ void emb1_kernel(const float* __restrict__ coor, const float* __restrict__ w,
                            const float* __restrict__ b, float* __restrict__ out) {
  int o = blockIdx.x * 256 + threadIdx.x;
  if (o >= RTOT * DD) return;
  int c = o & 255, r = o >> 8;
  float v = coor[r * 2] * w[c * 2] + coor[r * 2 + 1] * w[c * 2 + 1] + b[c];
  out[o] = fmaxf(v, 0.f);
}

// ---- generic broadcast-row GEMM + bias + relu ----
__global__ __launch_bounds__(512) void gemmB_kernel(const float* __restrict__ A, int lda,
                                                    const float* __restrict__ WT,
                                                    const float* __restrict__ bias,
                                                    float* __restrict__ C, int ldc, int coff,
                                                    int kshift) {
  __shared__ __align__(16) float As[8 * 1024];
  int K = 1 << kshift;
  int tid = threadIdx.x;
  int r0 = blockIdx.x * 8;
  for (int idx = tid; idx < 8 * K; idx += 512)
    As[idx] = A[(r0 + (idx >> kshift)) * lda + (idx & (K - 1))];
  __syncthreads();
  int d = tid & 255;
  int half = __builtin_amdgcn_readfirstlane(tid >> 8);
  float acc[4] = {};
  const float* asb = As + half * 4 * K;
  for (int kq = 0; kq < (K >> 2); kq++) {
    float4 wv = *(const float4*)(WT + kq * 1024 + d * 4);
    #pragma unroll
    for (int rr = 0; rr < 4; rr++) {
      float4 a4 = *(const float4*)(asb + rr * K + kq * 4);
      FMA4(acc[rr], a4, wv);
    }
  }
  float bv = bias[d];
  #pragma unroll
  for (int rr = 0; rr < 4; rr++)
    C[(r0 + half * 4 + rr) * ldc + coff + d] = fmaxf(acc[rr] + bv, 0.f);
}

// ---- internet kernel: one block per (b,k); k=3 blocks also dec() the previous rollout ----
__global__ __launch_bounds__(512) void internet_kernel(
    int j, const float* __restrict__ obj, const float* __restrict__ sbuf,
    const float* __restrict__ src_coor, float* __restrict__ dout,
    const float* __restrict__ rbuf, float* __restrict__ cs,
    const float* __restrict__ selfT, const float* __restrict__ uT,
    const float* __restrict__ vT, const float* __restrict__ affT,
    const float* __restrict__ outAT, const float* __restrict__ outST,
    const float* __restrict__ self_b, const float* __restrict__ rel_b,
    const float* __restrict__ aff_b, const float* __restrict__ out_b,
    const float* __restrict__ decw, const float* __restrict__ decb) {
  __shared__ __align__(16) float s_lds[6 * 256];
  __shared__ __align__(16) float v_lds[6 * 256];
  __shared__ __align__(16) float h_lds[6 * 256];
  __shared__ __align__(16) float a_lds[6 * 256];
  __shared__ float coor_lds[12], r_lds[6], mw[6][8];
  int bx = blockIdx.x;
  int xcd = bx & 7;
  int k = __builtin_amdgcn_readfirstlane(xcd >> 1);
  int b = __builtin_amdgcn_readfirstlane(((xcd & 1) << 5) + (bx >> 3));
  int sl = j + k;
  int tid = threadIdx.x;
  const float* srow = (sl < 4) ? (obj + (b * 4 + sl) * 6 * 256)
                               : (sbuf + ((sl - 4) * 64 + b) * 6 * 256);
  for (int idx = tid; idx < 1536; idx += 512) s_lds[idx] = srow[idx];
  if (tid < 6) r_lds[tid] = rbuf[b * 6 + tid];
  bool dodec = (k == 3) && (j >= 1);
  if (!dodec && tid < 12) {
    int i = tid >> 1, c = tid & 1;
    coor_lds[tid] = (sl < 4) ? src_coor[((b * 4 + sl) * 6 + i) * 2 + c]
                             : dout[((b * 8 + (sl - 4)) * 6 + i) * 4 + 2 + c];
  }
  __syncthreads();
  if (dodec && tid < 384) {
    int lane16 = tid & 15;
    int p = tid >> 4;
    int i = p >> 2, o = p & 3;
    float a2 = 0.f;
    #pragma unroll
    for (int m = 0; m < 16; m++) {
      int dd = lane16 + m * 16;
      a2 = fmaf(s_lds[i * 256 + dd], decw[o * 256 + dd], a2);
    }
    a2 += __shfl_down(a2, 8, 16);
    a2 += __shfl_down(a2, 4, 16);
    a2 += __shfl_down(a2, 2, 16);
    a2 += __shfl_down(a2, 1, 16);
    if (lane16 == 0) {
      float val = a2 + decb[o];
      dout[((b * 8 + (j - 1)) * 6 + i) * 4 + o] = val;
      if (o >= 2) coor_lds[i * 2 + (o - 2)] = val;
    }
  }
  __syncthreads();
  if (tid < 36) {
    int i = tid / 6, jj = tid % 6;
    float dx = coor_lds[i * 2] - coor_lds[jj * 2];
    float dy = coor_lds[i * 2 + 1] - coor_lds[jj * 2 + 1];
    float dist = sqrtf(dx * dx + dy * dy);
    mw[i][jj] = (i != jj && dist <= r_lds[i] + r_lds[jj]) ? 1.f : 0.f;
  }
  int d = tid & 255;
  int half = __builtin_amdgcn_readfirstlane(tid >> 8);
  const float* sT = selfT + k * 65536;
  const float* uTk = uT + k * 65536;
  const float* vTk = vT + k * 65536;
  const float* sbase = s_lds + half * 3 * 256;
  float as[3] = {}, au[3] = {}, av[3] = {};
  for (int kq = 0; kq < 64; kq++) {
    float4 ws = *(const float4*)(sT + kq * 1024 + d * 4);
    float4 wu = *(const float4*)(uTk + kq * 1024 + d * 4);
    float4 wv = *(const float4*)(vTk + kq * 1024 + d * 4);
    #pragma unroll
    for (int rr = 0; rr < 3; rr++) {
      float4 a4 = *(const float4*)(sbase + rr * 256 + kq * 4);
      FMA4(as[rr], a4, ws);
      FMA4(au[rr], a4, wu);
      FMA4(av[rr], a4, wv);
    }
  }
  #pragma unroll
  for (int rr = 0; rr < 3; rr++) v_lds[(half * 3 + rr) * 256 + d] = av[rr];
  __syncthreads();
  float sbv = self_b[k * 256 + d];
  float rbv = rel_b[k * 256 + d];
  #pragma unroll
  for (int rr = 0; rr < 3; rr++) {
    int i = half * 3 + rr;
    float cnt = mw[i][0] + mw[i][1] + mw[i][2] + mw[i][3] + mw[i][4] + mw[i][5];
    float relsum = cnt * (au[rr] + rbv);
    #pragma unroll
    for (int jj = 0; jj < 6; jj++)
      relsum = fmaf(mw[i][jj], v_lds[jj * 256 + d], relsum);
    h_lds[i * 256 + d] = as[rr] + sbv + relsum;
  }
  __syncthreads();
  const float* aT = affT + k * 65536;
  const float* hbase = h_lds + half * 3 * 256;
  float aa[3] = {};
  for (int kq = 0; kq < 64; kq++) {
    float4 wv = *(const float4*)(aT + kq * 1024 + d * 4);
    #pragma unroll
    for (int rr = 0; rr < 3; rr++) {
      float4 a4 = *(const float4*)(hbase + rr * 256 + kq * 4);
      FMA4(aa[rr], a4, wv);
    }
  }
  float abv = aff_b[k * 256 + d];
  #pragma unroll
  for (int rr = 0; rr < 3; rr++)
    a_lds[(half * 3 + rr) * 256 + d] = fmaxf(aa[rr] + abv, 0.f);
  __syncthreads();
  const float* oaT = outAT + k * 65536;
  const float* osT = outST + k * 65536;
  const float* abase = a_lds + half * 3 * 256;
  float ao[3] = {};
  for (int kq = 0; kq < 64; kq++) {
    float4 wa = *(const float4*)(oaT + kq * 1024 + d * 4);
    float4 wsv = *(const float4*)(osT + kq * 1024 + d * 4);
    #pragma unroll
    for (int rr = 0; rr < 3; rr++) {
      float4 a4 = *(const float4*)(abase + rr * 256 + kq * 4);
      float4 s4 = *(const float4*)(sbase + rr * 256 + kq * 4);
      FMA4(ao[rr], a4, wa);
      FMA4(ao[rr], s4, wsv);
    }
  }
  float obv = out_b[k * 256 + d];
  #pragma unroll
  for (int rr = 0; rr < 3; rr++)
    cs[(b * 6 + half * 3 + rr) * 1024 + k * 256 + d] = fmaxf(ao[rr] + obv, 0.f);
}

// ---- agg (d-sliced 4-wide): block (b, dq) computes sn[b][:, dq*64..+63], no relu ----
__global__ __launch_bounds__(512) void agg4_kernel(int j, const float* __restrict__ cs,
                                                   const float* __restrict__ aggT,
                                                   const float* __restrict__ agg_b,
                                                   float* __restrict__ sbuf) {
  __shared__ __align__(16) float cs_lds[6 * 1024];
  int bx = blockIdx.x;
  int dq = bx & 3;
  int b = bx >> 2;
  int tid = threadIdx.x;
  for (int idx = tid; idx < 6144; idx += 512) cs_lds[idx] = cs[b * 6144 + idx];
  __syncthreads();
  int d = tid & 63;
  int i = tid >> 6;
  if (i < 6) {
    float acc = 0.f;
    const float* wp = aggT + (dq * 64 + d) * 4;
    const float* ap = cs_lds + i * 1024;
    for (int kq = 0; kq < 256; kq++) {
      float4 wv = *(const float4*)(wp + kq * 1024);
      float4 a4 = *(const float4*)(ap + kq * 4);
      FMA4(acc, a4, wv);
    }
    sbuf[((j * 64 + b) * 6 + i) * 256 + dq * 64 + d] = acc + agg_b[dq * 64 + d];
  }
}

// ---- final dec for rollout 7 ----
__global__ void dec_last(const float* __restrict__ sbuf, const float* __restrict__ decw,
                         const float* __restrict__ decb, float* __restrict__ dout) {
  int b = blockIdx.x;
  int tid = threadIdx.x;   // 384
  int lane16 = tid & 15;
  int p = tid >> 4;
  int i = p >> 2, o = p & 3;
  const float* sp = sbuf + ((size_t)(7 * 64 + b) * 6 + i) * 256;
  float a2 = 0.f;
  #pragma unroll
  for (int m = 0; m < 16; m++) {
    int dd = lane16 + m * 16;
    a2 = fmaf(sp[dd], decw[o * 256 + dd], a2);
  }
  a2 += __shfl_down(a2, 8, 16);
  a2 += __shfl_down(a2, 4, 16);
  a2 += __shfl_down(a2, 2, 16);
  a2 += __shfl_down(a2, 1, 16);
  if (lane16 == 0) dout[((b * 8 + 7) * 6 + i) * 4 + o] = a2 + decb[o];
}

extern "C" void kernel_launch(void* const* d_in, const int* in_sizes, int n_in,
                              void* d_out, int out_size, void* d_ws, size_t ws_size,
                              hipStream_t stream) {
  const float* x        = (const float*)d_in[0];
  const float* rois     = (const float*)d_in[1];
  const float* src_coor = (const float*)d_in[2];
  const float* w_conv1  = (const float*)d_in[3];
  const float* b_conv1  = (const float*)d_in[4];
  const float* w_conv2  = (const float*)d_in[5];
  const float* b_conv2  = (const float*)d_in[6];
  const float* fc0_w    = (const float*)d_in[7];
  const float* fc0_b    = (const float*)d_in[8];
  const float* fc0c_w   = (const float*)d_in[9];
  const float* fc0c_b   = (const float*)d_in[10];
  const float* fc1c_w   = (const float*)d_in[11];
  const float* fc1c_b   = (const float*)d_in[12];
  const float* red_w    = (const float*)d_in[13];
  const float* red_b    = (const float*)d_in[14];
  const float* g_self_w = (const float*)d_in[15];
  const float* g_self_b = (const float*)d_in[16];
  const float* g_rel_w  = (const float*)d_in[17];
  const float* g_rel_b  = (const float*)d_in[18];
  const float* g_aff_w  = (const float*)d_in[19];
  const float* g_aff_b  = (const float*)d_in[20];
  const float* g_out_w  = (const float*)d_in[21];
  const float* g_out_b  = (const float*)d_in[22];
  const float* agg_w    = (const float*)d_in[23];
  const float* agg_b    = (const float*)d_in[24];
  const float* dec_w    = (const float*)d_in[25];
  const float* dec_b    = (const float*)d_in[26];
  float* out = (float*)d_out;

  float* ws = (float*)d_ws;
  size_t off = 0;
  auto alloc = [&](size_t nf) { float* p = ws + off; off += (nf + 63) & ~(size_t)63; return p; };
  float* feat2 = alloc(16777216);   // (256,64,32,32)
  float* pool  = alloc(1572864);    // (1536,1024)
  float* cat   = alloc(786432);     // (1536,512)
  float* emb1  = alloc(393216);     // (1536,256)
  float* obj   = alloc(393216);     // (B,T,N,256) = state slots 0..3
  float* sbuf  = alloc(786432);     // (8,B,N,256) = state slots 4..11
  float* cs    = alloc(393216);     // (B,N,1024)
  float* rbuf  = alloc(384);
  float* fc0T  = alloc(262144);
  float* fc1cT = alloc(65536);
  float* redT  = alloc(131072);
  float* aggT  = alloc(262144);
  float* selfT = alloc(262144);
  float* uT    = alloc(262144);
  float* vT    = alloc(262144);
  float* affT  = alloc(262144);
  float* outAT = alloc(262144);
  float* outST = alloc(262144);
  float* w1p   = alloc(1728);
  ushort_t* w2fh = (ushort_t*)alloc(18432);   // 36864 bf16
  ushort_t* w2fl = (ushort_t*)alloc(18432);

  MatDescs md;
  int mi = 0;
  auto add = [&](const float* s, float* dstp, int ksh, int stride, int coff) {
    md.m[mi].src = s; md.m[mi].dst = dstp; md.m[mi].kshift = ksh;
    md.m[mi].stride = stride; md.m[mi].coff = coff; mi++;
  };
  add(fc0_w,  fc0T,  10, 1024, 0);
  add(fc1c_w, fc1cT, 8,  256,  0);
  add(red_w,  redT,  9,  512,  0);
  add(agg_w,  aggT,  10, 1024, 0);
  for (int k = 0; k < 4; k++) {
    add(g_self_w + k * 65536,  selfT + k * 65536, 8, 256, 0);
    add(g_rel_w  + k * 131072, uT    + k * 65536, 8, 512, 0);
    add(g_rel_w  + k * 131072, vT    + k * 65536, 8, 512, 256);
    add(g_aff_w  + k * 65536,  affT  + k * 65536, 8, 256, 0);
    add(g_out_w  + k * 131072, outAT + k * 65536, 8, 512, 0);
    add(g_out_w  + k * 131072, outST + k * 65536, 8, 512, 256);
  }

  prep_mats<<<dim3(1024, 28), dim3(256), 0, stream>>>(md);
  prep_convw2<<<dim3(152), dim3(256), 0, stream>>>(w_conv1, w_conv2, w1p, w2fh, w2fl);
  r_kernel<<<dim3(2), dim3(256), 0, stream>>>(rois, rbuf);
  convmf_kernel<<<dim3(8192), dim3(512), 0, stream>>>(x, w1p, b_conv1, w2fh, w2fl, b_conv2, feat2);
  roi_pool_kernel<<<dim3(6144), dim3(256), 0, stream>>>(feat2, rois, pool);
  gemmB_kernel<<<dim3(192), dim3(512), 0, stream>>>(pool, 1024, fc0T, fc0_b, cat, 512, 0, 10);
  emb1_kernel<<<dim3(1536), dim3(256), 0, stream>>>(src_coor, fc0c_w, fc0c_b, emb1);
  gemmB_kernel<<<dim3(192), dim3(512), 0, stream>>>(emb1, 256, fc1cT, fc1c_b, cat, 512, 256, 8);
  gemmB_kernel<<<dim3(192), dim3(512), 0, stream>>>(cat, 512, redT, red_b, obj, 256, 0, 9);
  for (int j = 0; j < 8; j++) {
    internet_kernel<<<dim3(256), dim3(512), 0, stream>>>(j, obj, sbuf, src_coor, out, rbuf, cs,
        selfT, uT, vT, affT, outAT, outST, g_self_b, g_rel_b, g_aff_b, g_out_b, dec_w, dec_b);
    agg4_kernel<<<dim3(256), dim3(512), 0, stream>>>(j, cs, aggT, agg_b, sbuf);
  }
  dec_last<<<dim3(64), dim3(384), 0, stream>>>(sbuf, dec_w, dec_b, out);
  (void)in_sizes; (void)n_in; (void)out_size; (void)ws_size;
}